// Round 5
// baseline (496.463 us; speedup 1.0000x reference)
//
#include <hip/hip_runtime.h>
#include <hip/hip_fp16.h>

#define BB 512
#define TT 2048

typedef _Float16 half2v __attribute__((ext_vector_type(2)));

// ---------- fast math helpers ----------
__device__ __forceinline__ float fexp2(float x){ return __builtin_amdgcn_exp2f(x); }
__device__ __forceinline__ float frcp(float x){ return __builtin_amdgcn_rcpf(x); }
__device__ __forceinline__ float sigm(float x){ return frcp(1.f + fexp2(-1.4426950408889634f*x)); }
__device__ __forceinline__ float tanhfast(float x){ return 1.f - 2.f*frcp(1.f + fexp2(2.8853900817779268f*x)); }

#define QB(v, ctrl) __int_as_float(__builtin_amdgcn_mov_dpp(__float_as_int(v), (ctrl), 0xF, 0xF, true))
#define RL(v, l)    __builtin_amdgcn_readlane((v), (l))

// ---------- pass 1: xg[b][tg][e][u] = f16( -k_q * preact ), 53 rows ----------
// (byte-identical to the verified round-0 kernel; ~48 us, not the bottleneck)
__global__ __launch_bounds__(256) void k_xg3(const float* __restrict__ x,
                                             const float* __restrict__ Wih,
                                             const float* __restrict__ bih,
                                             const float* __restrict__ bhh,
                                             const float* __restrict__ fcb,
                                             unsigned* __restrict__ xg_u)
{
  __shared__ float    xs[13*256];
  __shared__ unsigned ot[32*212];      // 32 tg x 424 ushorts (53 rows x 8) = 848B/tg
  const int tid = threadIdx.x;
  const int b   = blockIdx.x >> 3;
  const int t0  = (blockIdx.x & 7) << 8;

  const float* xsrc = x + ((size_t)b*TT + t0)*13;
  #pragma unroll
  for (int it=0; it<13; ++it) xs[tid + it*256] = xsrc[tid + it*256];
  __syncthreads();

  float xv[13];
  #pragma unroll
  for (int k=0;k<13;k++) xv[k] = xs[tid*13+k];

  const int tgl = tid >> 3, u = tid & 7;
  unsigned short* otp = (unsigned short*)ot;
  #pragma unroll 2
  for (int g=0; g<52; ++g){            // g = q*13+j; q==2 <=> 26<=g<39
    float acc = bih[g] + bhh[g];
    #pragma unroll
    for (int k=0;k<13;k++) acc = fmaf(Wih[g*13+k], xv[k], acc);
    const float sc = (g>=26 && g<39) ? -2.8853900817779268f : -1.4426950408889634f;
    otp[tgl*424 + g*8 + u] = __half_as_ushort(__float2half(acc*sc));
  }
  // FC row (52): constant -log2e*fc_b
  otp[tgl*424 + 52*8 + u] =
      __half_as_ushort(__float2half(-1.4426950408889634f * fcb[0]));
  __syncthreads();

  unsigned* dst = xg_u + (size_t)b*(256*212) + (size_t)(blockIdx.x & 7)*(32*212);
  #pragma unroll
  for (int it=0; it<27; ++it){
    int i2 = tid + it*256;
    if (i2 < 32*212) dst[i2] = ot[i2];
  }
}

// ---------- pass 2: DUAL-CHAIN recurrence + fused FC ----------
// One wave runs TWO independent batch chains (b0 = 2*blk, b1 = 2*blk+1),
// interleaved at STEP granularity. The single chain is latency-bound
// (240 cy/step, ~82 issue-cy): chain B's non-convergent ops fill chain A's
// dependency bubbles; issue budget 2x82=164 < 240 so not issue-bound.
// lane 4j+q = gate q of unit j; lane 52 computes the FC output in-stream.
__global__ __launch_bounds__(64, 1) void k_rec8(const float* __restrict__ Whh,
                                                const float* __restrict__ fcw,
                                                const float* __restrict__ fcb,
                                                const unsigned short* __restrict__ xg,
                                                float* __restrict__ out)
{
  const int lane = threadIdx.x;
  const int b0   = blockIdx.x*2;
  const int b1   = b0 + 1;
  const int q    = lane & 3;
  const int j    = lane >> 2;             // 0..15 (13..15 padding)
  const int jc   = (j < 13) ? j : 12;
  const int e    = (lane == 52) ? 52 : q*13 + jc;

  const float kq = (q==2) ? -2.8853900817779268f : -1.4426950408889634f;
  const float gm = (q==2) ? -5.7707801635558536f : 1.f;
  const float ga = (q==2) ?  2.8853900817779268f : 0.f;
  const float fcbias = -1.4426950408889634f * fcb[0];

  const float* wsrc = (lane == 52) ? fcw : (Whh + e*13);
  float w[13];
  #pragma unroll
  for (int k=0;k<13;k++) w[k] = wsrc[k]*kq;

  const char* gbaseA = (const char*)xg + (size_t)b0*(256*848) + (size_t)e*16;
  const char* gbaseB = (const char*)xg + (size_t)b1*(256*848) + (size_t)e*16;

  float hA = 0.f, cA_ = 0.f, hB = 0.f, cB_ = 0.f;   // c*_ carries -2*log2e*c
  float hbA0=0,hbA1=0,hbA2=0,hbA3=0,hbA4=0,hbA5=0,hbA6=0,hbA7=0,hbA8=0,hbA9=0,hbA10=0,hbA11=0,hbA12=0;
  float hbB0=0,hbB1=0,hbB2=0,hbB3=0,hbB4=0,hbB5=0,hbB6=0,hbB7=0,hbB8=0,hbB9=0,hbB10=0,hbB11=0,hbB12=0;

  float pA0=0,pA1=0,pA2=0,pA3=0,pA4=0,pA5=0,pA6=0,pA7=0;
  float pB0=0,pB1=0,pB2=0,pB3=0,pB4=0,pB5=0,pB6=0,pB7=0;
  float* opA = out + (size_t)b0*TT;
  float* opB = out + (size_t)b1*TT;
  bool firstA = true, firstB = true;

#define CAPTURE(S, gv_, u_) do {                                              \
    if ((u_)==1) p##S##0=(gv_); else if ((u_)==2) p##S##1=(gv_);              \
    else if ((u_)==3) p##S##2=(gv_); else if ((u_)==4) p##S##3=(gv_);         \
    else if ((u_)==5) p##S##4=(gv_); else if ((u_)==6) p##S##5=(gv_);         \
    else if ((u_)==7) p##S##6=(gv_);                                          \
    else { p##S##7=(gv_);                                                     \
      if (!first##S){                                                         \
        if (lane == 52){                                                      \
          float4* o4 = (float4*)op##S;                                        \
          o4[0] = make_float4(p##S##0,p##S##1,p##S##2,p##S##3);               \
          o4[1] = make_float4(p##S##4,p##S##5,p##S##6,p##S##7);               \
        }                                                                     \
        op##S += 8;                                                           \
      }                                                                       \
      first##S = false;                                                       \
    }                                                                         \
  } while(0)

#define STEP(S, xv_, u_) do {                                                 \
    float dA = fmaf(w[0], hb##S##0, (xv_));                                   \
    dA = fmaf(w[1], hb##S##1, dA);                                            \
    dA = fmaf(w[2], hb##S##2, dA);                                            \
    dA = fmaf(w[3], hb##S##3, dA);                                            \
    dA = fmaf(w[4], hb##S##4, dA);                                            \
    float dB = w[5]*hb##S##5;                                                 \
    dB = fmaf(w[6], hb##S##6, dB);                                            \
    dB = fmaf(w[7], hb##S##7, dB);                                            \
    dB = fmaf(w[8], hb##S##8, dB);                                            \
    float dC = w[9]*hb##S##9;                                                 \
    dC = fmaf(w[10], hb##S##10, dC);                                          \
    dC = fmaf(w[11], hb##S##11, dC);                                          \
    dC = fmaf(w[12], hb##S##12, dC);                                          \
    float s  = (dB + dC) + dA;                                                \
    float r  = frcp(1.f + fexp2(s));                                          \
    float g  = fmaf(gm, r, ga);                                               \
    CAPTURE(S, g, u_);                                                        \
    float ggb = QB(g, 0xAA);                                                  \
    float gfb = QB(g, 0x55);                                                  \
    float gob = QB(g, 0xFF);                                                  \
    float go2 = gob + gob;                                                    \
    c##S##_ = fmaf(gfb, c##S##_, g*ggb);                                      \
    float r2 = frcp(1.f + fexp2(c##S##_));                                    \
    h##S = fmaf(go2, r2, -gob);                                               \
    int hv_ = __float_as_int(h##S);                                           \
    hb##S##0  = __int_as_float(RL(hv_, 0));                                   \
    hb##S##1  = __int_as_float(RL(hv_, 4));                                   \
    hb##S##2  = __int_as_float(RL(hv_, 8));                                   \
    hb##S##3  = __int_as_float(RL(hv_, 12));                                  \
    hb##S##4  = __int_as_float(RL(hv_, 16));                                  \
    hb##S##5  = __int_as_float(RL(hv_, 20));                                  \
    hb##S##6  = __int_as_float(RL(hv_, 24));                                  \
    hb##S##7  = __int_as_float(RL(hv_, 28));                                  \
    hb##S##8  = __int_as_float(RL(hv_, 32));                                  \
    hb##S##9  = __int_as_float(RL(hv_, 36));                                  \
    hb##S##10 = __int_as_float(RL(hv_, 40));                                  \
    hb##S##11 = __int_as_float(RL(hv_, 44));                                  \
    hb##S##12 = __int_as_float(RL(hv_, 48));                                  \
  } while(0)

#define XLO(w_) (float)(__builtin_bit_cast(half2v, (w_)).x)
#define XHI(w_) (float)(__builtin_bit_cast(half2v, (w_)).y)

// 8 timesteps of BOTH chains, interleaved per-step for ILP
#define STEP8PAIR(QA, QB) do {                                                \
    STEP(A, XLO(QA.x), 0); STEP(B, XLO(QB.x), 0);                             \
    STEP(A, XHI(QA.x), 1); STEP(B, XHI(QB.x), 1);                             \
    STEP(A, XLO(QA.y), 2); STEP(B, XLO(QB.y), 2);                             \
    STEP(A, XHI(QA.y), 3); STEP(B, XHI(QB.y), 3);                             \
    STEP(A, XLO(QA.z), 4); STEP(B, XLO(QB.z), 4);                             \
    STEP(A, XHI(QA.z), 5); STEP(B, XHI(QB.z), 5);                             \
    STEP(A, XLO(QA.w), 6); STEP(B, XLO(QB.w), 6);                             \
    STEP(A, XHI(QA.w), 7); STEP(B, XHI(QB.w), 7);                             \
  } while(0)

  // 2-row (16-step) register prefetch per chain: ~2200+ cy cover >> HBM latency
  uint4 qA0 = *(const uint4*)(gbaseA);
  uint4 qA1 = *(const uint4*)(gbaseA + 848);
  uint4 qB0 = *(const uint4*)(gbaseB);
  uint4 qB1 = *(const uint4*)(gbaseB + 848);

  for (int i=0; i<127; ++i){
    const char* pA = gbaseA + (size_t)(2*i+2)*848;
    const char* pB = gbaseB + (size_t)(2*i+2)*848;
    uint4 cA = qA0; qA0 = *(const uint4*)(pA);
    uint4 cB = qB0; qB0 = *(const uint4*)(pB);
    STEP8PAIR(cA, cB);
    cA = qA1; qA1 = *(const uint4*)(pA + 848);
    cB = qB1; qB1 = *(const uint4*)(pB + 848);
    STEP8PAIR(cA, cB);
  }
  STEP8PAIR(qA0, qB0);
  STEP8PAIR(qA1, qB1);

  // epilogue: out[2047] = sigmoid(fc_b + fc_w·h_2047) for both chains
  {
    float sA = fcbias;
    sA = fmaf(w[0],  hbA0,  sA);
    sA = fmaf(w[1],  hbA1,  sA);
    sA = fmaf(w[2],  hbA2,  sA);
    sA = fmaf(w[3],  hbA3,  sA);
    sA = fmaf(w[4],  hbA4,  sA);
    sA = fmaf(w[5],  hbA5,  sA);
    sA = fmaf(w[6],  hbA6,  sA);
    sA = fmaf(w[7],  hbA7,  sA);
    sA = fmaf(w[8],  hbA8,  sA);
    sA = fmaf(w[9],  hbA9,  sA);
    sA = fmaf(w[10], hbA10, sA);
    sA = fmaf(w[11], hbA11, sA);
    sA = fmaf(w[12], hbA12, sA);
    float rA = frcp(1.f + fexp2(sA));
    float sB = fcbias;
    sB = fmaf(w[0],  hbB0,  sB);
    sB = fmaf(w[1],  hbB1,  sB);
    sB = fmaf(w[2],  hbB2,  sB);
    sB = fmaf(w[3],  hbB3,  sB);
    sB = fmaf(w[4],  hbB4,  sB);
    sB = fmaf(w[5],  hbB5,  sB);
    sB = fmaf(w[6],  hbB6,  sB);
    sB = fmaf(w[7],  hbB7,  sB);
    sB = fmaf(w[8],  hbB8,  sB);
    sB = fmaf(w[9],  hbB9,  sB);
    sB = fmaf(w[10], hbB10, sB);
    sB = fmaf(w[11], hbB11, sB);
    sB = fmaf(w[12], hbB12, sB);
    float rB = frcp(1.f + fexp2(sB));
    if (lane == 52){
      float4* o4 = (float4*)opA;          // opA == out + b0*TT + 2040 here
      o4[0] = make_float4(pA0,pA1,pA2,pA3);
      o4[1] = make_float4(pA4,pA5,pA6,rA);
      o4 = (float4*)opB;
      o4[0] = make_float4(pB0,pB1,pB2,pB3);
      o4[1] = make_float4(pB4,pB5,pB6,rB);
    }
  }

#undef STEP8PAIR
#undef STEP
#undef CAPTURE
#undef XLO
#undef XHI
}

// ---------- fallback (no workspace) ----------
__global__ __launch_bounds__(64) void k_rec_fb(
    const float* __restrict__ x,   const float* __restrict__ Whh,
    const float* __restrict__ Wih, const float* __restrict__ bih, const float* __restrict__ bhh,
    const float* __restrict__ fcw, const float* __restrict__ fcb,
    float* __restrict__ out)
{
  const int lane = threadIdx.x;
  const int c    = lane >> 4;
  const int j    = lane & 15;
  const int b    = blockIdx.x*4 + c;
  const bool act = (j < 13);
  const int jj   = act ? j : 0;

  float whh[4][13], wih[4][13], bias[4];
  #pragma unroll
  for (int q=0;q<4;q++){
    #pragma unroll
    for (int k=0;k<13;k++){
      float w1 = Whh[(q*13+jj)*13 + k];
      float w2 = Wih[(q*13+jj)*13 + k];
      whh[q][k] = act ? w1 : 0.f;
      wih[q][k] = act ? w2 : 0.f;
    }
    bias[q] = bih[q*13+jj] + bhh[q*13+jj];
  }
  const float fcwj = act ? fcw[jj] : 0.f;
  const float fcb0 = fcb[0];

  const float* xpf = x + (size_t)b*(TT*13) + jj;
  float* op = out + (size_t)b*TT;

  float h = 0.f, cs = 0.f;
  float xsc = *xpf;

  for (int t=0; t<TT; ++t){
    float xscn = 0.f;
    if (t+1 < TT) { xpf += 13; xscn = *xpf; }

    float hb[13], xb[13];
    {
      int hbits = __float_as_int(h);
      int xbits = __float_as_int(xsc);
      #define HB(k) hb[k] = __int_as_float(__builtin_amdgcn_ds_swizzle(hbits, ((k)<<5)|0x10)); \
                    xb[k] = __int_as_float(__builtin_amdgcn_ds_swizzle(xbits, ((k)<<5)|0x10));
      HB(0) HB(1) HB(2) HB(3) HB(4) HB(5) HB(6) HB(7) HB(8) HB(9) HB(10) HB(11) HB(12)
      #undef HB
    }
    float a0 = bias[0], a1 = bias[1], a2 = bias[2], a3 = bias[3];
    #pragma unroll
    for (int k=0;k<13;k++){
      float xk = xb[k], hk = hb[k];
      a0 += wih[0][k]*xk + whh[0][k]*hk;
      a1 += wih[1][k]*xk + whh[1][k]*hk;
      a2 += wih[2][k]*xk + whh[2][k]*hk;
      a3 += wih[3][k]*xk + whh[3][k]*hk;
    }
    float ig = sigm(a0), fg = sigm(a1), gg = tanhfast(a2), og = sigm(a3);
    cs = fg*cs + ig*gg;
    h  = og * tanhfast(cs);

    float p = act ? fcwj*h : 0.f;
    #define RED(m) p += __int_as_float(__builtin_amdgcn_ds_swizzle(__float_as_int(p), ((m)<<10)|0x1F));
    RED(1) RED(2) RED(4) RED(8)
    #undef RED
    if (j == 0) op[t] = sigm(p + fcb0);
    xsc = xscn;
  }
}

extern "C" void kernel_launch(void* const* d_in, const int* in_sizes, int n_in,
                              void* d_out, int out_size, void* d_ws, size_t ws_size,
                              hipStream_t stream)
{
  const float* x   = (const float*)d_in[0];
  const float* Wih = (const float*)d_in[1];
  const float* Whh = (const float*)d_in[2];
  const float* bih = (const float*)d_in[3];
  const float* bhh = (const float*)d_in[4];
  const float* fcw = (const float*)d_in[5];
  const float* fcb = (const float*)d_in[6];
  float* out = (float*)d_out;

  const size_t XG_BYTES = (size_t)BB*256*848;     // 111,149,056  f16 [b][tg][53][8]

  if (ws_size >= XG_BYTES){
    unsigned* xg = (unsigned*)d_ws;
    k_xg3<<<dim3(BB*8), dim3(256), 0, stream>>>(x, Wih, bih, bhh, fcb, xg);
    k_rec8<<<dim3(BB/2), dim3(64), 0, stream>>>(Whh, fcw, fcb,
                                                (const unsigned short*)xg, out);
  } else {
    k_rec_fb<<<dim3(BB/4), dim3(64), 0, stream>>>(x, Whh, Wih, bih, bhh, fcw, fcb, out);
  }
}

// Round 6
// 308.390 us; speedup vs baseline: 1.6099x; 1.6099x over previous
//
#include <hip/hip_runtime.h>
#include <hip/hip_fp16.h>

#define BB 512
#define TT 2048

typedef _Float16 half2v __attribute__((ext_vector_type(2)));

// ---------- fast math helpers ----------
__device__ __forceinline__ float fexp2(float x){ return __builtin_amdgcn_exp2f(x); }
__device__ __forceinline__ float frcp(float x){ return __builtin_amdgcn_rcpf(x); }

#define QB(v, ctrl) __int_as_float(__builtin_amdgcn_mov_dpp(__float_as_int(v), (ctrl), 0xF, 0xF, true))
#define RL(v, l)    __builtin_amdgcn_readlane((v), (l))

// ---------- fused producer/consumer, round 6 ----------
// Block = 128 threads (2 waves) per batch element b. KEY DIFFERENCE vs rounds 2-4:
// the consumer's seed path is BYTE-IDENTICAL to the proven 205us k_rec7 (f16 rows,
// uint4/ds_read_b128 loads, same 848B/tg layout) -- only the address space changed
// (global xg -> LDS chunk). The producer wave emits the exact k_xg3 row format.
//   LDS: 2 chunk buffers x 8 tg x 424 ushorts (53 rows x 8 f16) = 13,568 B.
//   producer (wave 1): per chunk, 52 dots of 13 (weights via scalar cache, x via
//     13 coalesced per-lane dwords prefetched one chunk ahead) + f16 cvt +
//     ds_write_b16. ~1.7K issue-cy per chunk << consumer's 15.4K cy -> always early.
//   consumer (wave 0): k_rec7 verbatim. lane 4j+q = gate q of unit j; lane 52
//     computes the fused FC output in-stream. Per chunk: 8x ds_read_b128, 64 STEPs.
//   sync: 1 __syncthreads per 64 steps (32 total), double-buffered.
__global__ __launch_bounds__(128, 1) void k_pc(
    const float* __restrict__ x,
    const float* __restrict__ Wih,
    const float* __restrict__ Whh,
    const float* __restrict__ bih,
    const float* __restrict__ bhh,
    const float* __restrict__ fcw,
    const float* __restrict__ fcb,
    float* __restrict__ out)
{
  __shared__ unsigned short xgb[2][8][424];   // [buf][tg][53 rows x 8 u]

  const int tid  = threadIdx.x;
  const int wid  = tid >> 6;
  const int lane = tid & 63;
  const int b    = blockIdx.x;

  // ---- producer state (persists across chunk loop)
  float xr[13];
  const int  tgl = lane >> 3, u = lane & 7;
  const float* xbase = x + ((size_t)b*TT + tgl*8 + u)*13;   // t = c*64 + tgl*8 + u
  unsigned short fc16 = 0;

  // ---- consumer state (persists across chunk loop; k_rec7 verbatim)
  float w[13];
  float gm = 1.f, ga = 0.f, fcbias = 0.f;
  int   e = 0;
  float h = 0.f, c_ = 0.f;            // c_ carries -2*log2e*c
  float hb0=0,hb1=0,hb2=0,hb3=0,hb4=0,hb5=0,hb6=0,hb7=0,hb8=0,hb9=0,hb10=0,hb11=0,hb12=0;
  float p0=0,p1=0,p2=0,p3=0,p4=0,p5=0,p6=0,p7=0;
  float* op = out + (size_t)b*TT;
  bool first = true;

// producer: load chunk c_'s 13 x values (coalesced per-lane dwords; issued one
// chunk ahead -- the full consumer chunk (~15K cy) covers HBM latency)
#define XLOAD(c_) do {                                                        \
    const float* p_ = xbase + (size_t)(c_)*64*13;                             \
    _Pragma("unroll")                                                         \
    for (int k=0;k<13;++k) xr[k] = p_[k];                                     \
  } while(0)

// producer: compute + write one chunk in the exact k_xg3 row format
#define FILL(bi_) do {                                                        \
    unsigned short* dst_ = &xgb[bi_][tgl][0];                                 \
    _Pragma("unroll 4")                                                       \
    for (int g=0; g<52; ++g){                                                 \
      float acc = bih[g] + bhh[g];                                            \
      _Pragma("unroll")                                                       \
      for (int k=0;k<13;++k) acc = fmaf(Wih[g*13+k], xr[k], acc);             \
      const float sc = (g>=26 && g<39) ? -2.8853900817779268f                 \
                                       : -1.4426950408889634f;                \
      dst_[g*8 + u] = __half_as_ushort(__float2half(acc*sc));                 \
    }                                                                         \
    dst_[52*8 + u] = fc16;                                                    \
  } while(0)

#define CAPTURE(gv_, u_) do {                                                 \
    if ((u_)==1) p0=(gv_); else if ((u_)==2) p1=(gv_);                        \
    else if ((u_)==3) p2=(gv_); else if ((u_)==4) p3=(gv_);                   \
    else if ((u_)==5) p4=(gv_); else if ((u_)==6) p5=(gv_);                   \
    else if ((u_)==7) p6=(gv_);                                               \
    else { p7=(gv_);                                                          \
      if (!first){                                                            \
        if (lane == 52){                                                      \
          float4* o4 = (float4*)op;                                           \
          o4[0] = make_float4(p0,p1,p2,p3);                                   \
          o4[1] = make_float4(p4,p5,p6,p7);                                   \
        }                                                                     \
        op += 8;                                                              \
      }                                                                       \
      first = false;                                                          \
    }                                                                         \
  } while(0)

#define STEP(xv_, u_) do {                                                    \
    float dA = fmaf(w[0], hb0, (xv_));                                        \
    dA = fmaf(w[1], hb1, dA);                                                 \
    dA = fmaf(w[2], hb2, dA);                                                 \
    dA = fmaf(w[3], hb3, dA);                                                 \
    dA = fmaf(w[4], hb4, dA);                                                 \
    float dB = w[5]*hb5;                                                      \
    dB = fmaf(w[6], hb6, dB);                                                 \
    dB = fmaf(w[7], hb7, dB);                                                 \
    dB = fmaf(w[8], hb8, dB);                                                 \
    float dC = w[9]*hb9;                                                      \
    dC = fmaf(w[10], hb10, dC);                                               \
    dC = fmaf(w[11], hb11, dC);                                               \
    dC = fmaf(w[12], hb12, dC);                                               \
    float s  = (dB + dC) + dA;                                                \
    float r  = frcp(1.f + fexp2(s));                                          \
    float g  = fmaf(gm, r, ga);                                               \
    CAPTURE(g, u_);                                                           \
    float ggb = QB(g, 0xAA);                                                  \
    float gfb = QB(g, 0x55);                                                  \
    float gob = QB(g, 0xFF);                                                  \
    float go2 = gob + gob;                                                    \
    c_ = fmaf(gfb, c_, g*ggb);                                                \
    float r2 = frcp(1.f + fexp2(c_));                                         \
    h = fmaf(go2, r2, -gob);                                                  \
    int hv_ = __float_as_int(h);                                              \
    hb0  = __int_as_float(RL(hv_, 0));                                        \
    hb1  = __int_as_float(RL(hv_, 4));                                        \
    hb2  = __int_as_float(RL(hv_, 8));                                        \
    hb3  = __int_as_float(RL(hv_, 12));                                       \
    hb4  = __int_as_float(RL(hv_, 16));                                       \
    hb5  = __int_as_float(RL(hv_, 20));                                       \
    hb6  = __int_as_float(RL(hv_, 24));                                       \
    hb7  = __int_as_float(RL(hv_, 28));                                       \
    hb8  = __int_as_float(RL(hv_, 32));                                       \
    hb9  = __int_as_float(RL(hv_, 36));                                       \
    hb10 = __int_as_float(RL(hv_, 40));                                       \
    hb11 = __int_as_float(RL(hv_, 44));                                       \
    hb12 = __int_as_float(RL(hv_, 48));                                       \
  } while(0)

#define XLO(w_) (float)(__builtin_bit_cast(half2v, (w_)).x)
#define XHI(w_) (float)(__builtin_bit_cast(half2v, (w_)).y)

#define STEP8(Q) do {                                                         \
    STEP(XLO(Q.x), 0); STEP(XHI(Q.x), 1);                                     \
    STEP(XLO(Q.y), 2); STEP(XHI(Q.y), 3);                                     \
    STEP(XLO(Q.z), 4); STEP(XHI(Q.z), 5);                                     \
    STEP(XLO(Q.w), 6); STEP(XHI(Q.w), 7);                                     \
  } while(0)

// consumer: one chunk = 8 tg rows, k_rec7's uint4 row loads from LDS
#define CONSUME(bi_) do {                                                     \
    const char* base_ = (const char*)&xgb[bi_][0][0] + (size_t)e*16;          \
    uint4 r0 = *(const uint4*)(base_ + 0*848);                                \
    uint4 r1 = *(const uint4*)(base_ + 1*848);                                \
    uint4 r2 = *(const uint4*)(base_ + 2*848);                                \
    uint4 r3 = *(const uint4*)(base_ + 3*848);                                \
    uint4 r4 = *(const uint4*)(base_ + 4*848);                                \
    uint4 r5 = *(const uint4*)(base_ + 5*848);                                \
    uint4 r6 = *(const uint4*)(base_ + 6*848);                                \
    uint4 r7 = *(const uint4*)(base_ + 7*848);                                \
    STEP8(r0); STEP8(r1); STEP8(r2); STEP8(r3);                               \
    STEP8(r4); STEP8(r5); STEP8(r6); STEP8(r7);                               \
  } while(0)

  if (wid == 1){
    // -------- producer setup + chunk 0 --------
    fc16 = __half_as_ushort(__float2half(-1.4426950408889634f * fcb[0]));
    XLOAD(0);
    FILL(0);
    XLOAD(1);                 // prefetch chunk 1 (consumed next FILL)
  } else {
    // -------- consumer setup (k_rec7 verbatim) --------
    const int q  = lane & 3;
    const int j  = lane >> 2;             // 0..15 (13..15 padding)
    const int jc = (j < 13) ? j : 12;
    e = (lane == 52) ? 52 : q*13 + jc;
    const float kq = (q==2) ? -2.8853900817779268f : -1.4426950408889634f;
    gm = (q==2) ? -5.7707801635558536f : 1.f;
    ga = (q==2) ?  2.8853900817779268f : 0.f;
    fcbias = -1.4426950408889634f * fcb[0];
    const float* wsrc = (lane == 52) ? fcw : (Whh + (size_t)e*13);
    #pragma unroll
    for (int k=0;k<13;k++) w[k] = wsrc[k]*kq;
  }
  __syncthreads();                                  // chunk 0 ready

  for (int c=0; c<31; ++c){
    if (wid == 1){
      FILL((c+1)&1);                                // chunk c+1 (uses prefetched xr)
      if (c < 30) XLOAD(c+2);                       // prefetch chunk c+2
    } else {
      CONSUME(c&1);                                 // chunk c
    }
    __syncthreads();                                // chunk c+1 ready
  }

  if (wid == 0){
    CONSUME(31&1);                                  // chunk 31

    // epilogue: out[2047] = sigmoid(fc_b + fc_w·h_2047); lane 52 stores p0..p6 + r
    float s = fcbias;
    s = fmaf(w[0],  hb0,  s);
    s = fmaf(w[1],  hb1,  s);
    s = fmaf(w[2],  hb2,  s);
    s = fmaf(w[3],  hb3,  s);
    s = fmaf(w[4],  hb4,  s);
    s = fmaf(w[5],  hb5,  s);
    s = fmaf(w[6],  hb6,  s);
    s = fmaf(w[7],  hb7,  s);
    s = fmaf(w[8],  hb8,  s);
    s = fmaf(w[9],  hb9,  s);
    s = fmaf(w[10], hb10, s);
    s = fmaf(w[11], hb11, s);
    s = fmaf(w[12], hb12, s);
    float r = frcp(1.f + fexp2(s));
    if (lane == 52){
      float4* o4 = (float4*)op;                     // op == out + b*TT + 2040 here
      o4[0] = make_float4(p0,p1,p2,p3);
      o4[1] = make_float4(p4,p5,p6,r);
    }
  }

#undef CONSUME
#undef STEP8
#undef STEP
#undef CAPTURE
#undef FILL
#undef XLOAD
#undef XLO
#undef XHI
}

extern "C" void kernel_launch(void* const* d_in, const int* in_sizes, int n_in,
                              void* d_out, int out_size, void* d_ws, size_t ws_size,
                              hipStream_t stream)
{
  const float* x   = (const float*)d_in[0];
  const float* Wih = (const float*)d_in[1];
  const float* Whh = (const float*)d_in[2];
  const float* bih = (const float*)d_in[3];
  const float* bhh = (const float*)d_in[4];
  const float* fcw = (const float*)d_in[5];
  const float* fcb = (const float*)d_in[6];
  float* out = (float*)d_out;

  (void)d_ws; (void)ws_size;   // fully fused: no workspace
  k_pc<<<dim3(BB), dim3(128), 0, stream>>>(x, Wih, Whh, bih, bhh, fcw, fcb, out);
}